// Round 14
// baseline (202.749 us; speedup 1.0000x reference)
//
#include <hip/hip_runtime.h>
#include <hip/hip_bf16.h>

// out[b, d] = sum_k sc[b,k] * dict[serp(d), k]    B=262144, K=32, D=900.
//
// R9-R13: five schedule variants (alternation, dbuf, 2-block, prod/consumer)
// all land 194-203us (~5.0 TB/s effective) -> schedule falsified as lever.
// Residual vs 143us idealized floor includes 4 sequential ROUNDS of blocks:
// 4x prologue (dict gather + sc loads + cvt) + 4x ramp/tail skew.
// R14: ONE round. 256 blocks x 1024 rows (TILES=64), 1 block/CU. sc
// fragments reload in groups of 8 tiles: issue loads one tile before the
// group boundary, convert at the boundary -> compiler emits counted
// vmcnt(~15) once per 8 tiles (mild dip, not a drain). Everything else is
// R11's loop verbatim: zero other vmem reads, lgkm-only barriers,
// fill-pattern copy, 2x57.6KB LDS double buffer.

typedef __attribute__((ext_vector_type(8))) short bf16x8;
typedef __attribute__((ext_vector_type(4))) float f32x4;

constexpr int KD    = 32;
constexpr int DDIM  = 900;
constexpr int SDIM  = 30;
constexpr int NCHT  = 57;              // 16-col chunks (57*16 = 912)
constexpr int TROWS = 16;              // rows per tile (= MFMA n)
constexpr int GROUP = 8;               // tiles per sc-reload group
constexpr int NGRP  = 8;               // groups per block
constexpr int TILES = GROUP * NGRP;    // 64 tiles
constexpr int RPB   = TROWS * TILES;   // 1024 rows per block -> 256 blocks
constexpr int TFL   = TROWS * DDIM;    // 14400 floats per staging buffer

__device__ __forceinline__ int serp_src(int d) {
    int r = d / SDIM, c = d - r * SDIM;
    return (r & 1) ? (r * SDIM + (SDIM - 1 - c)) : d;
}

__device__ __forceinline__ short f2bf(float x) {
    __hip_bfloat16 h = __float2bfloat16(x);   // RNE
    short u; __builtin_memcpy(&u, &h, 2); return u;
}

// Barrier ordering LDS only: waits own ds ops, does NOT drain global stores.
__device__ __forceinline__ void barrier_lds() {
    __builtin_amdgcn_sched_barrier(0);
    asm volatile("s_waitcnt lgkmcnt(0)" ::: "memory");
    __builtin_amdgcn_sched_barrier(0);
    __builtin_amdgcn_s_barrier();
    __builtin_amdgcn_sched_barrier(0);
}

__global__ __launch_bounds__(256, 1) void mfma_decode(
    const float* __restrict__ sc,     // [B, 32]
    const float* __restrict__ dict,   // [900, 32]
    float* __restrict__ out,          // [B, 900]
    int B)
{
    __shared__ alignas(16) float stg[2][TFL];   // 115200 B double buffer

    const int t    = threadIdx.x;
    const int lane = t & 63;
    const int wid  = t >> 6;                    // 0..3

    const int brow = lane & 15;             // D col (n) -> b-row within tile
    const int k0   = (lane >> 4) << 3;      // fragment k offset
    const int dloc = (lane >> 4) << 2;      // D row (m) base -> d offset in chunk
    const long long b0 = (long long)blockIdx.x * RPB;

    // ---- dict fragments df[15]: wave wid owns chunks wid+4j ----
    // A-fragment layout: m = lane&15 (d within chunk), k = (lane>>4)*8 + j.
    bf16x8 df[15];
    #pragma unroll
    for (int j = 0; j < 15; ++j) {
        int ch = wid + 4 * j; if (ch > NCHT - 1) ch = NCHT - 1;   // dup, unused
        int d  = ch * 16 + (lane & 15);
        int dd = (d < DDIM) ? d : (DDIM - 1);                     // pad lanes
        const float* p = dict + (size_t)serp_src(dd) * KD + k0;
        const float4 f0 = *reinterpret_cast<const float4*>(p);
        const float4 f1 = *reinterpret_cast<const float4*>(p + 4);
        bf16x8 a;
        a[0] = f2bf(f0.x); a[1] = f2bf(f0.y); a[2] = f2bf(f0.z); a[3] = f2bf(f0.w);
        a[4] = f2bf(f1.x); a[5] = f2bf(f1.y); a[6] = f2bf(f1.z); a[7] = f2bf(f1.w);
        df[j] = a;
    }

    // sc raw-load for one group (16 float4 per lane, short liveness).
    float4 ra[GROUP], rb[GROUP];
    auto load_group = [&](int g) {
        #pragma unroll
        for (int u = 0; u < GROUP; ++u) {
            const long long tt = (long long)g * GROUP + u;
            const float* ap = sc + (size_t)(b0 + tt * TROWS + brow) * KD + k0;
            ra[u] = *reinterpret_cast<const float4*>(ap);
            rb[u] = *reinterpret_cast<const float4*>(ap + 4);
        }
    };

    bf16x8 bb[GROUP];
    auto cvt_group = [&]() {
        #pragma unroll
        for (int u = 0; u < GROUP; ++u) {
            bf16x8 r;
            r[0] = f2bf(ra[u].x); r[1] = f2bf(ra[u].y);
            r[2] = f2bf(ra[u].z); r[3] = f2bf(ra[u].w);
            r[4] = f2bf(rb[u].x); r[5] = f2bf(rb[u].y);
            r[6] = f2bf(rb[u].z); r[7] = f2bf(rb[u].w);
            bb[u] = r;
        }
    };

    // MFMA pass for one tile -> staging buffer buf.
    auto compute = [&](const bf16x8& bbx, float* buf) {
        #pragma unroll
        for (int j = 0; j < 15; ++j) {
            const int ch = wid + 4 * j;
            if (ch < NCHT) {                         // wave-uniform
                f32x4 z = {0.f, 0.f, 0.f, 0.f};
                f32x4 acc = __builtin_amdgcn_mfma_f32_16x16x32_bf16(df[j], bbx, z, 0, 0, 0);
                if (ch != 56) {
                    *reinterpret_cast<f32x4*>(&buf[brow * DDIM + ch * 16 + dloc]) = acc;
                } else if (dloc == 0) {              // only d=896..899 valid
                    *reinterpret_cast<f32x4*>(&buf[brow * DDIM + 896]) = acc;
                }
            }
        }
    };

    // ---- prologue (once per GPU: exactly 1 round of 256 blocks) ----
    load_group(0);
    cvt_group();
    compute(bb[0], stg[0]);
    barrier_lds();

    const int base = t * 4;

    for (int g = 0; g < NGRP; ++g) {             // dynamic outer loop
        #pragma unroll
        for (int u = 0; u < GROUP; ++u) {        // static inner indices
            const long long tile = (long long)g * GROUP + u;

            // Issue next group's sc loads one tile before the boundary:
            // cvt at u==7 then waits counted vmcnt(~15) -- a dip, not a drain.
            if (u == GROUP - 2 && g + 1 < NGRP) load_group(g + 1);

            // ---- compute tile+1 into the other buffer ----
            if (u < GROUP - 1) {
                compute(bb[u + 1], stg[(u + 1) & 1]);
            } else if (g + 1 < NGRP) {
                cvt_group();                     // overwrites bb[0..7]
                compute(bb[0], stg[(u + 1) & 1]);
            }

            // ---- copy tile from stg[u&1]: literal fill pattern ----
            float* __restrict__ tbase = out + (size_t)(b0 + tile * TROWS) * DDIM;
            const float* __restrict__ buf = stg[u & 1];
            #pragma unroll
            for (int i = 0; i < 14; ++i) {
                const int o = i * 1024 + base;   // 14*1024 = 14336
                f32x4 v = *reinterpret_cast<const f32x4*>(&buf[o]);
                *reinterpret_cast<f32x4*>(tbase + o) = v;
            }
            if (t < 16) {                        // 14336 + 64 = 14400
                const int o = 14336 + base;
                f32x4 v = *reinterpret_cast<const f32x4*>(&buf[o]);
                *reinterpret_cast<f32x4*>(tbase + o) = v;
            }

            barrier_lds();                       // stores stay in flight
        }
    }
}

extern "C" void kernel_launch(void* const* d_in, const int* in_sizes, int n_in,
                              void* d_out, int out_size, void* d_ws, size_t ws_size,
                              hipStream_t stream) {
    const float* sc   = (const float*)d_in[0];   // [B, 32]
    const float* dict = (const float*)d_in[1];   // [900, 32]
    float* out        = (float*)d_out;           // [B, 1, 30, 30] flat = [B, 900]

    const int B = in_sizes[0] / KD;              // 262144 (divisible by RPB=1024)

    mfma_decode<<<dim3((unsigned)(B / RPB)), 256, 0, stream>>>(sc, dict, out, B);
}

// Round 15
// 195.525 us; speedup vs baseline: 1.0369x; 1.0369x over previous
//
#include <hip/hip_runtime.h>
#include <hip/hip_bf16.h>

// out[b, d] = sum_k sc[b,k] * dict[serp(d), k]    B=262144, K=32, D=900.
//
// FINAL (revert to R11, best measured: 194.3us = ~5.0 TB/s effective).
// Ladder: 643 (fp32 lane-per-d) -> 396 (LDS-staged sc) -> 321 (bf16 MFMA)
// -> 291 (operand swap, float4 stores) -> 232 (full-row staging + fill-
// pattern copy) -> 219 (lgkm-only barriers) -> 203 (full-tile staging)
// -> 194 (zero-vmem steady loop). R10/R12/R13/R14 (dbuf scheduling,
// 2-block, producer/consumer, 1-round amortization) all null: the ceiling
// is the LDS-fed dependent-store drain rate (~74% of immediate-data fill).
//
// Structure: 1 block/CU, 256 threads. Dict fragments (serpentine-remapped,
// bf16, MFMA A-layout) and ALL 16 tiles' sc fragments preloaded to registers
// in the prologue -> the steady loop has ZERO vmem reads and ZERO vmcnt
// waits: global stores ride the queue at max depth on pure backpressure.
// Per tile: mfma(dict, sc) -> 16x900 tile in LDS (double-buffered) ->
// literal fill-pattern contiguous dwordx4 copy to out. Barriers are
// lgkm-only (never drain stores).

typedef __attribute__((ext_vector_type(8))) short bf16x8;
typedef __attribute__((ext_vector_type(4))) float f32x4;

constexpr int KD    = 32;
constexpr int DDIM  = 900;
constexpr int SDIM  = 30;
constexpr int NCHT  = 57;              // 16-col chunks (57*16 = 912)
constexpr int TROWS = 16;              // rows per tile (= MFMA n)
constexpr int TILES = 16;              // tiles per block
constexpr int RPB   = TROWS * TILES;   // 256 rows per block -> 1024 blocks
constexpr int TFL   = TROWS * DDIM;    // 14400 floats per staging buffer

__device__ __forceinline__ int serp_src(int d) {
    int r = d / SDIM, c = d - r * SDIM;
    return (r & 1) ? (r * SDIM + (SDIM - 1 - c)) : d;
}

__device__ __forceinline__ short f2bf(float x) {
    __hip_bfloat16 h = __float2bfloat16(x);   // RNE
    short u; __builtin_memcpy(&u, &h, 2); return u;
}

// Barrier ordering LDS only: waits own ds ops, does NOT drain global stores.
__device__ __forceinline__ void barrier_lds() {
    __builtin_amdgcn_sched_barrier(0);
    asm volatile("s_waitcnt lgkmcnt(0)" ::: "memory");
    __builtin_amdgcn_sched_barrier(0);
    __builtin_amdgcn_s_barrier();
    __builtin_amdgcn_sched_barrier(0);
}

__global__ __launch_bounds__(256, 1) void mfma_decode(
    const float* __restrict__ sc,     // [B, 32]
    const float* __restrict__ dict,   // [900, 32]
    float* __restrict__ out,          // [B, 900]
    int B)
{
    __shared__ alignas(16) float stg[2][TFL];   // 115200 B double buffer

    const int t    = threadIdx.x;
    const int lane = t & 63;
    const int wid  = t >> 6;

    const int brow = lane & 15;             // D col (n) -> b-row within tile
    const int k0   = (lane >> 4) << 3;      // fragment k offset
    const int dloc = (lane >> 4) << 2;      // D row (m) base -> d offset in chunk
    const long long b0 = (long long)blockIdx.x * RPB;

    // ---- prologue 1: issue ALL sc loads (16 tiles x 2 float4 per lane) ----
    float4 ra[TILES], rb[TILES];
    #pragma unroll
    for (int tt = 0; tt < TILES; ++tt) {
        const float* ap = sc + (size_t)(b0 + tt * TROWS + brow) * KD + k0;
        ra[tt] = *reinterpret_cast<const float4*>(ap);
        rb[tt] = *reinterpret_cast<const float4*>(ap + 4);
    }

    // ---- prologue 2: dict fragments df[15]: wave wid owns chunks wid+4j ----
    // A-fragment layout: m = lane&15 (-> d within chunk), k = (lane>>4)*8 + j.
    bf16x8 df[15];
    #pragma unroll
    for (int j = 0; j < 15; ++j) {
        int ch = wid + 4 * j; if (ch > NCHT - 1) ch = NCHT - 1;   // dup, unused
        int d  = ch * 16 + (lane & 15);
        int dd = (d < DDIM) ? d : (DDIM - 1);                     // pad lanes
        const float* p = dict + (size_t)serp_src(dd) * KD + k0;
        const float4 f0 = *reinterpret_cast<const float4*>(p);
        const float4 f1 = *reinterpret_cast<const float4*>(p + 4);
        bf16x8 a;
        a[0] = f2bf(f0.x); a[1] = f2bf(f0.y); a[2] = f2bf(f0.z); a[3] = f2bf(f0.w);
        a[4] = f2bf(f1.x); a[5] = f2bf(f1.y); a[6] = f2bf(f1.z); a[7] = f2bf(f1.w);
        df[j] = a;
    }

    // ---- prologue 3: convert all sc fragments to bf16 (statically indexed) ----
    bf16x8 bb[TILES];
    #pragma unroll
    for (int tt = 0; tt < TILES; ++tt) {
        bf16x8 r;
        r[0] = f2bf(ra[tt].x); r[1] = f2bf(ra[tt].y);
        r[2] = f2bf(ra[tt].z); r[3] = f2bf(ra[tt].w);
        r[4] = f2bf(rb[tt].x); r[5] = f2bf(rb[tt].y);
        r[6] = f2bf(rb[tt].z); r[7] = f2bf(rb[tt].w);
        bb[tt] = r;
    }

    // MFMA pass for one tile -> staging buffer buf.
    auto compute = [&](const bf16x8& bbx, float* buf) {
        #pragma unroll
        for (int j = 0; j < 15; ++j) {
            const int ch = wid + 4 * j;
            if (ch < NCHT) {                         // wave-uniform
                f32x4 z = {0.f, 0.f, 0.f, 0.f};
                f32x4 acc = __builtin_amdgcn_mfma_f32_16x16x32_bf16(df[j], bbx, z, 0, 0, 0);
                if (ch != 56) {
                    *reinterpret_cast<f32x4*>(&buf[brow * DDIM + ch * 16 + dloc]) = acc;
                } else if (dloc == 0) {              // only d=896..899 valid
                    *reinterpret_cast<f32x4*>(&buf[brow * DDIM + 896]) = acc;
                }
            }
        }
    };

    compute(bb[0], stg[0]);
    barrier_lds();

    const int base = t * 4;

    // ---- steady loop: NO vmem reads, NO vmcnt waits. Fully unrolled so all
    // bb[] indexing is static (rule #20). ----
    #pragma unroll
    for (int tile = 0; tile < TILES; ++tile) {
        // compute tile+1 into the other buffer (MFMA + ds_write pipes)
        if (tile + 1 < TILES) compute(bb[tile + 1], stg[(tile + 1) & 1]);

        // copy tile from stg[tile&1]: literal fill pattern, contiguous
        float* __restrict__ tbase = out + (size_t)(b0 + (long long)tile * TROWS) * DDIM;
        const float* __restrict__ buf = stg[tile & 1];
        #pragma unroll
        for (int i = 0; i < 14; ++i) {
            const int o = i * 1024 + base;           // 14*1024 = 14336
            f32x4 v = *reinterpret_cast<const f32x4*>(&buf[o]);
            *reinterpret_cast<f32x4*>(tbase + o) = v;
        }
        if (t < 16) {                                // 14336 + 64 = 14400
            const int o = 14336 + base;
            f32x4 v = *reinterpret_cast<const f32x4*>(&buf[o]);
            *reinterpret_cast<f32x4*>(tbase + o) = v;
        }

        if (tile + 1 < TILES) barrier_lds();         // stores stay in flight
    }
}

extern "C" void kernel_launch(void* const* d_in, const int* in_sizes, int n_in,
                              void* d_out, int out_size, void* d_ws, size_t ws_size,
                              hipStream_t stream) {
    const float* sc   = (const float*)d_in[0];   // [B, 32]
    const float* dict = (const float*)d_in[1];   // [900, 32]
    float* out        = (float*)d_out;           // [B, 1, 30, 30] flat = [B, 900]

    const int B = in_sizes[0] / KD;              // 262144 (divisible by RPB=256)

    mfma_decode<<<dim3((unsigned)(B / RPB)), 256, 0, stream>>>(sc, dict, out, B);
}